// Round 4
// baseline (162.789 us; speedup 1.0000x reference)
//
#include <hip/hip_runtime.h>
#include <hip/hip_bf16.h>
#include <math.h>

namespace {
constexpr int V = 50000, E = 256, H = 512, S = 500, B = 64, OOVN = 50;
constexpr int VEXT = V + OOVN;   // 50050
constexpr int CCAT = E + 3 * H;  // 1792  (embed | h_new | context)
constexpr int G3 = 3 * H;        // 1536
constexpr int NLB = 391;         // logits gemm blocks (3128 waves, 3125 active)

typedef __attribute__((ext_vector_type(8))) short short8;
typedef __attribute__((ext_vector_type(4))) float f32x4;

__device__ __forceinline__ float wsum(float v) {
#pragma unroll
  for (int off = 32; off > 0; off >>= 1) v += __shfl_xor(v, off, 64);
  return v;
}
__device__ __forceinline__ float sigmoidf(float x) { return 1.f / (1.f + __expf(-x)); }
__device__ __forceinline__ float fast_tanh(float x) {
  x = fminf(fmaxf(x, -15.f), 15.f);
  float e = __expf(2.f * x);
  return __fdividef(e - 1.f, e + 1.f);
}
// online-softmax merge, safe for (m=-inf,l=0) empties
__device__ __forceinline__ void smerge_s(float& m, float& l, float om, float ol) {
  float nm = fmaxf(m, om);
  if (nm == -INFINITY) { m = nm; return; }
  l = l * __expf(m - nm) + ol * __expf(om - nm);
  m = nm;
}

__device__ __forceinline__ short bf16_rn_s(float f) {
  __hip_bfloat16 h = __float2bfloat16(f);
  return __builtin_bit_cast(short, h);
}
// split f into hi (bf16 truncate) + lo (bf16 rounded residual); f ~= hi + lo
__device__ __forceinline__ void hilo1(float f, short* hi, short* lo) {
  unsigned u = __float_as_uint(f);
  *hi = (short)(u >> 16);
  *lo = bf16_rn_s(f - __uint_as_float(u & 0xffff0000u));
}
__device__ __forceinline__ void hilo8(float4 a, float4 b, short8& hi, short8& lo) {
  float f[8] = {a.x, a.y, a.z, a.w, b.x, b.y, b.z, b.w};
#pragma unroll
  for (int i = 0; i < 8; ++i) {
    unsigned u = __float_as_uint(f[i]);
    hi[i] = (short)(u >> 16);
    lo[i] = bf16_rn_s(f[i] - __uint_as_float(u & 0xffff0000u));
  }
}

// ---- MFMA core (hi/lo accurate, compile-time K): wave computes C[0:64][n0:n0+16] ----
template <int KSTEPS>
__device__ __forceinline__ void gemm16(const short* __restrict__ Xhi,
                                       const short* __restrict__ Xlo, int ldx, int xk0,
                                       const float* __restrict__ W, int ldw, int wk0,
                                       int n0, float* __restrict__ C, int ldc) {
  const int l = threadIdx.x & 63;
  const int r16 = l & 15, q16 = l >> 4;
  f32x4 acc[4];
#pragma unroll
  for (int t = 0; t < 4; ++t) acc[t] = (f32x4){0.f, 0.f, 0.f, 0.f};

  const float* wp = W + (size_t)(n0 + r16) * ldw + wk0 + q16 * 8;
  const short* xh[4];
  const short* xl[4];
#pragma unroll
  for (int t = 0; t < 4; ++t) {
    int row = t * 16 + r16;
    xh[t] = Xhi + (size_t)row * ldx + xk0 + q16 * 8;
    xl[t] = Xlo + (size_t)row * ldx + xk0 + q16 * 8;
  }

#pragma unroll
  for (int ks = 0; ks < KSTEPS; ++ks) {
    const int ko = ks * 32;
    float4 w0 = *reinterpret_cast<const float4*>(wp + ko);
    float4 w1 = *reinterpret_cast<const float4*>(wp + ko + 4);
    short8 whi, wlo;
    hilo8(w0, w1, whi, wlo);
#pragma unroll
    for (int t = 0; t < 4; ++t) {
      short8 ah = *reinterpret_cast<const short8*>(xh[t] + ko);
      short8 al = *reinterpret_cast<const short8*>(xl[t] + ko);
      acc[t] = __builtin_amdgcn_mfma_f32_16x16x32_bf16(ah, whi, acc[t], 0, 0, 0);
      acc[t] = __builtin_amdgcn_mfma_f32_16x16x32_bf16(al, whi, acc[t], 0, 0, 0);
      acc[t] = __builtin_amdgcn_mfma_f32_16x16x32_bf16(ah, wlo, acc[t], 0, 0, 0);
    }
  }
#pragma unroll
  for (int t = 0; t < 4; ++t) {
#pragma unroll
    for (int r = 0; r < 4; ++r) {
      int row = t * 16 + q16 * 4 + r;
      C[(size_t)row * ldc + n0 + r16] = acc[t][r];
    }
  }
}

// ---- prep: h hi/lo split + embed gather ----
__global__ void k_prep(const int* __restrict__ tok, const float* __restrict__ emb,
                       const float* __restrict__ prevh, float* __restrict__ cc,
                       short* __restrict__ cch, short* __restrict__ ccl,
                       short* __restrict__ hh, short* __restrict__ hl) {
  int i = blockIdx.x * 256 + threadIdx.x;  // 32768
  hilo1(prevh[i], &hh[i], &hl[i]);
  if (i < 16384) {
    int b = i >> 8, e = i & 255;
    float v = emb[(size_t)tok[b] * E + e];
    cc[b * CCAT + e] = v;
    hilo1(v, &cch[b * CCAT + e], &ccl[b * CCAT + e]);
  }
}

// ---- fused: q (4 K-chunks of 128) + gh (2 K-chunks of 256) ----
__global__ void __launch_bounds__(256) k_gemm_qgh(
    const short* __restrict__ hh, const short* __restrict__ hl,
    const float* __restrict__ Wq, const float* __restrict__ Whh,
    float* __restrict__ qpart, float* __restrict__ ghp) {
  int w = blockIdx.x * 4 + (threadIdx.x >> 6);  // 0..319
  if (w < 128) {
    int c = w >> 5, nt = w & 31;
    gemm16<4>(hh, hl, H, c * 128, Wq, H, c * 128, nt * 16,
              qpart + (size_t)c * 64 * H, H);
  } else {
    int w2 = w - 128;
    int c = w2 / 96, nt = w2 % 96;
    gemm16<8>(hh, hl, H, c * 256, Whh, H, c * 256, nt * 16,
              ghp + (size_t)c * 64 * G3, G3);
  }
}

// ---- scores[s][b] = sum_h tanh(q+pk)*We ; wave per (s,b) ----
__global__ void k_scores(const float* __restrict__ qpart, const float* __restrict__ pk,
                         const float* __restrict__ We, float* __restrict__ scores) {
  int lane = threadIdx.x & 63;
  int gw = blockIdx.x * 4 + (threadIdx.x >> 6);  // 0..31999
  int s = gw >> 6, b = gw & 63;
  const float* q0 = qpart + b * H + lane * 8;
  const float* kr = pk + ((size_t)s * B + b) * H + lane * 8;
  const float* er = We + lane * 8;
  float part = 0.f;
#pragma unroll
  for (int i = 0; i < 2; ++i) {
    float4 qa = *reinterpret_cast<const float4*>(q0 + i * 4);
    float4 qb = *reinterpret_cast<const float4*>(q0 + 64 * H + i * 4);
    float4 qc = *reinterpret_cast<const float4*>(q0 + 128 * H + i * 4);
    float4 qd = *reinterpret_cast<const float4*>(q0 + 192 * H + i * 4);
    float4 kv = *reinterpret_cast<const float4*>(kr + i * 4);
    float4 ev = *reinterpret_cast<const float4*>(er + i * 4);
    part += fast_tanh(qa.x + qb.x + qc.x + qd.x + kv.x) * ev.x +
            fast_tanh(qa.y + qb.y + qc.y + qd.y + kv.y) * ev.y +
            fast_tanh(qa.z + qb.z + qc.z + qd.z + kv.z) * ev.z +
            fast_tanh(qa.w + qb.w + qc.w + qd.w + kv.w) * ev.w;
  }
  part = wsum(part);
  if (lane == 0) scores[s * B + b] = part;
}

// ---- column softmax over s -> alphasT[B][S] ----
__global__ void k_softmax_s(const float* __restrict__ scores, float* __restrict__ alphasT) {
  int b = blockIdx.x, t = threadIdx.x;  // 512 threads
  int w = t >> 6, lane = t & 63;
  __shared__ float rm[8], rl[8];
  float v = (t < S) ? scores[t * B + b] : -INFINITY;
  float m = v;
#pragma unroll
  for (int off = 32; off > 0; off >>= 1) m = fmaxf(m, __shfl_xor(m, off, 64));
  if (lane == 0) rm[w] = m;
  __syncthreads();
  float bm = rm[0];
#pragma unroll
  for (int i = 1; i < 8; ++i) bm = fmaxf(bm, rm[i]);
  float e = (t < S) ? __expf(v - bm) : 0.f;
  float sw = wsum(e);
  if (lane == 0) rl[w] = sw;
  __syncthreads();
  float tot = rl[0];
#pragma unroll
  for (int i = 1; i < 8; ++i) tot += rl[i];
  if (t < S) alphasT[b * S + t] = e / tot;
}

// ---- context partials over s-halves: ctxp[sh][b][1024] ----
__global__ void k_ctx(const float* __restrict__ alphasT, const float* __restrict__ ench,
                      float* __restrict__ ctxp) {
  int b = blockIdx.x, chf = blockIdx.y, sh = blockIdx.z;
  int t = threadIdx.x;  // 512
  __shared__ float sa[250];
  if (t < 250) sa[t] = alphasT[b * S + sh * 250 + t];
  __syncthreads();
  const float* base = ench + ((size_t)(sh * 250) * B + b) * 1024 + chf * 512 + t;
  float a0 = 0.f, a1 = 0.f;
#pragma unroll 8
  for (int s = 0; s < 250; s += 2) {
    a0 += sa[s] * base[(size_t)s * (B * 1024)];
    a1 += sa[s + 1] * base[(size_t)(s + 1) * (B * 1024)];
  }
  ctxp[((sh * B + b) * 1024) + chf * 512 + t] = a0 + a1;
}

// ---- combine ctx partials -> cc[b][768:1792] + hi/lo ----
__global__ void k_ctx2(const float* __restrict__ ctxp, float* __restrict__ cc,
                       short* __restrict__ cch, short* __restrict__ ccl) {
  int b = blockIdx.x, t = threadIdx.x;  // 64 x 256
  int c = t * 4;
  float4 v0 = *reinterpret_cast<const float4*>(&ctxp[(b * 1024) + c]);
  float4 v1 = *reinterpret_cast<const float4*>(&ctxp[((B + b) * 1024) + c]);
  float r[4] = {v0.x + v1.x, v0.y + v1.y, v0.z + v1.z, v0.w + v1.w};
#pragma unroll
  for (int i = 0; i < 4; ++i) {
    int col = 768 + c + i;
    cc[b * CCAT + col] = r[i];
    hilo1(r[i], &cch[b * CCAT + col], &ccl[b * CCAT + col]);
  }
}

// ---- big fused gemm: gi (5 chunks) + lin embed/ctx chunks (5) ----
__global__ void __launch_bounds__(256) k_gemm_big(
    const short* __restrict__ cch, const short* __restrict__ ccl,
    const float* __restrict__ Wih, const float* __restrict__ linW,
    float* __restrict__ gip, float* __restrict__ linpart) {
  int w = blockIdx.x * 4 + (threadIdx.x >> 6);  // 0..639
  if (w < 480) {
    int c = w / 96, nt = w % 96;
    int xk0 = (c == 0) ? 0 : 768 + (c - 1) * 256;
    int wk0 = c * 256;
    gemm16<8>(cch, ccl, CCAT, xk0, Wih, 1280, wk0, nt * 16,
              gip + (size_t)c * 64 * G3, G3);
  } else {
    int w2 = w - 480;
    int c = w2 >> 5, nt = w2 & 31;
    int k0 = (c == 0) ? 0 : 768 + (c - 1) * 256;
    gemm16<8>(cch, ccl, CCAT, k0, linW, CCAT, k0, nt * 16,
              linpart + (size_t)c * 64 * H, H);
  }
}

// ---- GRU gates + p_gen (fused): block per b, 512 threads ----
__global__ void k_gates(const float* __restrict__ gip, const float* __restrict__ ghp,
                        const float* __restrict__ bih, const float* __restrict__ bhh,
                        const float* __restrict__ prevh, const float* __restrict__ pgW,
                        const float* __restrict__ pgb, float* __restrict__ cc,
                        short* __restrict__ cch, short* __restrict__ ccl,
                        float* __restrict__ hout, float* __restrict__ pgsum) {
  int b = blockIdx.x, j = threadIdx.x;  // 64 x 512
  float ir = bih[j], iz = bih[512 + j], in_ = bih[1024 + j];
#pragma unroll
  for (int c = 0; c < 5; ++c) {
    const float* g = gip + (size_t)c * 64 * G3 + b * G3;
    ir += g[j]; iz += g[512 + j]; in_ += g[1024 + j];
  }
  float hr = bhh[j], hz = bhh[512 + j], hn = bhh[1024 + j];
#pragma unroll
  for (int c = 0; c < 2; ++c) {
    const float* g = ghp + (size_t)c * 64 * G3 + b * G3;
    hr += g[j]; hz += g[512 + j]; hn += g[1024 + j];
  }
  float r = sigmoidf(ir + hr);
  float z = sigmoidf(iz + hz);
  float n = fast_tanh(in_ + r * hn);
  float h = prevh[b * H + j];
  float hnew = (1.f - z) * n + z * h;
  hout[b * H + j] = hnew;
  cc[b * CCAT + E + j] = hnew;
  hilo1(hnew, &cch[b * CCAT + E + j], &ccl[b * CCAT + E + j]);
  // p_gen partial dot
  float acc = hnew * pgW[E + j];
  acc += cc[b * CCAT + 768 + j] * pgW[768 + j];
  acc += cc[b * CCAT + 1280 + j] * pgW[1280 + j];
  if (j < 256) acc += cc[b * CCAT + j] * pgW[j];
  acc = wsum(acc);
  __shared__ float sl[8];
  int w = j >> 6, lane = j & 63;
  if (lane == 0) sl[w] = acc;
  __syncthreads();
  if (j == 0) {
    float tot = pgb[0];
#pragma unroll
    for (int i = 0; i < 8; ++i) tot += sl[i];
    pgsum[b] = tot;
  }
}

// ---- lin h-chunks (2 x 256) ----
__global__ void __launch_bounds__(256) k_gemm_linh(const short* __restrict__ cch,
                                                   const short* __restrict__ ccl,
                                                   const float* __restrict__ linW,
                                                   float* __restrict__ linpart) {
  int w = blockIdx.x * 4 + (threadIdx.x >> 6);  // 0..63
  int c = w >> 5, nt = w & 31;
  int k0 = 256 + c * 256;
  gemm16<8>(cch, ccl, CCAT, k0, linW, CCAT, k0, nt * 16,
            linpart + (size_t)(5 + c) * 64 * H, H);
}

// ---- lin finalize: sum partials + bias -> lin bf16 ----
__global__ void k_linfin(const float* __restrict__ linpart, const float* __restrict__ linb,
                         short* __restrict__ lh) {
  int idx = blockIdx.x * 256 + threadIdx.x;  // 32768
  int b = idx >> 9, o = idx & 511;
  float v = linb[o];
#pragma unroll
  for (int c = 0; c < 7; ++c) v += linpart[(size_t)c * 64 * H + b * H + o];
  lh[idx] = bf16_rn_s(v);
}

// ---- logits gemm + per-block online-softmax partials ----
__global__ void __launch_bounds__(512) k_gemm_logits(
    const short* __restrict__ lh, const float* __restrict__ outW,
    const float* __restrict__ outb, float* __restrict__ logits,
    float* __restrict__ pm, float* __restrict__ pl) {
  __shared__ __align__(16) short xs[64 * 512];
  __shared__ float pml[8][64][2];
  char* xb = reinterpret_cast<char*>(xs);
  int tid = threadIdx.x;
#pragma unroll
  for (int k = 0; k < 8; ++k) {
    int m = k * 512 + tid;  // 16B chunk id, 4096 total
    int row = m >> 6;
    short8 v = *reinterpret_cast<const short8*>(lh + (size_t)m * 8);
    int byte = (m * 16) ^ ((row & 7) << 4);
    *reinterpret_cast<short8*>(xb + byte) = v;
  }
  __syncthreads();
  const int l = tid & 63;
  const int r16 = l & 15, q16 = l >> 4;
  const int wid = tid >> 6;
  const int waveId = blockIdx.x * 8 + wid;
  const bool active = waveId < V / 16;
  if (active) {
    const int n0 = waveId * 16;
    f32x4 acc[4];
#pragma unroll
    for (int t = 0; t < 4; ++t) acc[t] = (f32x4){0.f, 0.f, 0.f, 0.f};
    const float* wp = outW + (size_t)(n0 + r16) * H + q16 * 8;
    int arow[4], aswz[4];
#pragma unroll
    for (int t = 0; t < 4; ++t) {
      int row = t * 16 + r16;
      arow[t] = row * 1024 + q16 * 16;
      aswz[t] = (row & 7) << 4;
    }
#pragma unroll
    for (int ks = 0; ks < 16; ++ks) {
      float4 w0 = *reinterpret_cast<const float4*>(wp + ks * 32);
      float4 w1 = *reinterpret_cast<const float4*>(wp + ks * 32 + 4);
      short8 wh;
      wh[0] = bf16_rn_s(w0.x); wh[1] = bf16_rn_s(w0.y);
      wh[2] = bf16_rn_s(w0.z); wh[3] = bf16_rn_s(w0.w);
      wh[4] = bf16_rn_s(w1.x); wh[5] = bf16_rn_s(w1.y);
      wh[6] = bf16_rn_s(w1.z); wh[7] = bf16_rn_s(w1.w);
#pragma unroll
      for (int t = 0; t < 4; ++t) {
        short8 a = *reinterpret_cast<const short8*>(xb + ((arow[t] + ks * 64) ^ aswz[t]));
        acc[t] = __builtin_amdgcn_mfma_f32_16x16x32_bf16(a, wh, acc[t], 0, 0, 0);
      }
    }
    float bv = outb[n0 + r16];
#pragma unroll
    for (int t = 0; t < 4; ++t) {
#pragma unroll
      for (int r = 0; r < 4; ++r) {
        float y = acc[t][r] + bv;
        int row = t * 16 + q16 * 4 + r;
        logits[(size_t)row * V + n0 + r16] = y;
        // row-wise (m,l) over this wave's 16 cols (lanes differing in r16)
        float m = y;
#pragma unroll
        for (int off = 8; off > 0; off >>= 1) m = fmaxf(m, __shfl_xor(m, off, 64));
        float e = __expf(y - m);
#pragma unroll
        for (int off = 8; off > 0; off >>= 1) e += __shfl_xor(e, off, 64);
        if (r16 == 0) { pml[wid][row][0] = m; pml[wid][row][1] = e; }
      }
    }
  } else if (r16 == 0) {
#pragma unroll
    for (int t = 0; t < 4; ++t)
#pragma unroll
      for (int r = 0; r < 4; ++r) {
        int row = t * 16 + q16 * 4 + r;
        pml[wid][row][0] = -INFINITY;
        pml[wid][row][1] = 0.f;
      }
  }
  __syncthreads();
  if (tid < 64) {
    float m = pml[0][tid][0], lv = pml[0][tid][1];
#pragma unroll
    for (int i = 1; i < 8; ++i) smerge_s(m, lv, pml[i][tid][0], pml[i][tid][1]);
    pm[blockIdx.x * 64 + tid] = m;
    pl[blockIdx.x * 64 + tid] = lv;
  }
}

// ---- final: reduce partials -> probs in LDS -> scatter (LDS atomics) -> log -> out ----
__global__ void k_final(const float* __restrict__ logits, const float* __restrict__ pm,
                        const float* __restrict__ pl, const float* __restrict__ pgsum,
                        const int* __restrict__ extv, const float* __restrict__ alphasT,
                        float* __restrict__ out) {
  int b = blockIdx.x, c = blockIdx.y, t = threadIdx.x;  // 64 x 10, 256 thr
  __shared__ float sp_[5056];
  __shared__ float rm[4], rl[4];
  float m = -INFINITY, lv = 0.f;
  for (int i = t; i < NLB; i += 256) smerge_s(m, lv, pm[i * 64 + b], pl[i * 64 + b]);
#pragma unroll
  for (int off = 32; off > 0; off >>= 1) {
    float om = __shfl_xor(m, off, 64), ol = __shfl_xor(lv, off, 64);
    smerge_s(m, lv, om, ol);
  }
  int w = t >> 6, lane = t & 63;
  if (lane == 0) { rm[w] = m; rl[w] = lv; }
  __syncthreads();
  m = rm[0]; lv = rl[0];
#pragma unroll
  for (int i = 1; i < 4; ++i) smerge_s(m, lv, rm[i], rl[i]);
  float pg = sigmoidf(pgsum[b]);
  float scale = pg / lv;
  const int base = c * 5000;
  const int len = (c == 9) ? 5050 : 5000;
  const float* lr = logits + (size_t)b * V + base;
  for (int i = t; i < len; i += 256)
    sp_[i] = (i < 5000) ? scale * __expf(lr[i] - m) + 1e-12f : 1e-12f;
  __syncthreads();
  float wgt = 1.f - pg;
  for (int s = t; s < S; s += 256) {
    int idx = extv[b * S + s] - base;
    if ((unsigned)idx < (unsigned)len) atomicAdd(&sp_[idx], wgt * alphasT[b * S + s]);
  }
  __syncthreads();
  float* orow = out + (size_t)b * VEXT + base;
  for (int i = t; i < len; i += 256) orow[i] = logf(sp_[i]);
}
}  // namespace

extern "C" void kernel_launch(void* const* d_in, const int* in_sizes, int n_in,
                              void* d_out, int out_size, void* d_ws, size_t ws_size,
                              hipStream_t stream) {
  const int*   tok   = (const int*)d_in[0];
  const float* ench  = (const float*)d_in[1];
  const float* pk    = (const float*)d_in[2];
  const float* prevh = (const float*)d_in[4];
  const int*   extv  = (const int*)d_in[5];
  const float* emb   = (const float*)d_in[7];
  const float* Wq    = (const float*)d_in[8];
  const float* We    = (const float*)d_in[9];
  const float* Wih   = (const float*)d_in[10];
  const float* Whh   = (const float*)d_in[11];
  const float* bih   = (const float*)d_in[12];
  const float* bhh   = (const float*)d_in[13];
  const float* linW  = (const float*)d_in[14];
  const float* linb  = (const float*)d_in[15];
  const float* pgW   = (const float*)d_in[16];
  const float* pgb   = (const float*)d_in[17];
  const float* outW  = (const float*)d_in[18];
  const float* outb  = (const float*)d_in[19];

  float* out = (float*)d_out;
  float* ws = (float*)d_ws;

  float* qpart   = ws;                   // 4*64*512 = 131072
  float* scores  = qpart + 131072;       // 32000
  float* alphasT = scores + 32000;       // 32000
  float* ctxp    = alphasT + 32000;      // 2*64*1024 = 131072
  float* cc      = ctxp + 131072;        // 64*1792 = 114688
  float* gip     = cc + 114688;          // 5*64*1536 = 491520
  float* ghp     = gip + 491520;         // 2*64*1536 = 196608
  float* linpart = ghp + 196608;         // 7*64*512 = 229376
  float* pgsum   = linpart + 229376;     // 64
  float* logits  = pgsum + 64;           // 64*50000 = 3200000
  float* pm      = logits + 3200000;     // 391*64 = 25024
  float* pl      = pm + 25024;           // 25024
  short* sp      = (short*)(pl + 25024);
  short* cch = sp;                 // 114688
  short* ccl = cch + 114688;       // 114688
  short* hh  = ccl + 114688;       // 32768
  short* hl  = hh + 32768;         // 32768
  short* lh  = hl + 32768;         // 32768
  float* hout = out + (size_t)B * VEXT;

  k_prep<<<dim3(128), dim3(256), 0, stream>>>(tok, emb, prevh, cc, cch, ccl, hh, hl);
  k_gemm_qgh<<<dim3(80), dim3(256), 0, stream>>>(hh, hl, Wq, Whh, qpart, ghp);
  k_scores<<<dim3(8000), dim3(256), 0, stream>>>(qpart, pk, We, scores);
  k_softmax_s<<<dim3(B), dim3(512), 0, stream>>>(scores, alphasT);
  k_ctx<<<dim3(64, 2, 2), dim3(512), 0, stream>>>(alphasT, ench, ctxp);
  k_ctx2<<<dim3(B), dim3(256), 0, stream>>>(ctxp, cc, cch, ccl);
  k_gemm_big<<<dim3(160), dim3(256), 0, stream>>>(cch, ccl, Wih, linW, gip, linpart);
  k_gates<<<dim3(B), dim3(512), 0, stream>>>(gip, ghp, bih, bhh, prevh, pgW, pgb, cc, cch,
                                             ccl, hout, pgsum);
  k_gemm_linh<<<dim3(16), dim3(256), 0, stream>>>(cch, ccl, linW, linpart);
  k_linfin<<<dim3(128), dim3(256), 0, stream>>>(linpart, linb, lh);
  k_gemm_logits<<<dim3(NLB), dim3(512), 0, stream>>>(lh, outW, outb, logits, pm, pl);
  k_final<<<dim3(B, 10), dim3(256), 0, stream>>>(logits, pm, pl, pgsum, extv, alphasT, out);
}